// Round 2
// baseline (1088.550 us; speedup 1.0000x reference)
//
#include <hip/hip_runtime.h>

#define N_NODES 100000
#define N_EDGES 1600000
#define IN_FEATS 128
#define H_FEATS 128

// ---------------------------------------------------------------- degree hist
__global__ void degree_kernel(const int* __restrict__ src, const int* __restrict__ dst,
                              int* __restrict__ deg_out, int* __restrict__ deg_in) {
    int e = blockIdx.x * blockDim.x + threadIdx.x;
    if (e < N_EDGES) {
        atomicAdd(&deg_out[src[e]], 1);
        atomicAdd(&deg_in[dst[e]], 1);
    }
}

// ---------------------------------------------------------------- norms
__global__ void norm_kernel(const int* __restrict__ deg_out, const int* __restrict__ deg_in,
                            float* __restrict__ out_norm, float* __restrict__ in_norm) {
    int i = blockIdx.x * blockDim.x + threadIdx.x;
    if (i < N_NODES) {
        int dov = deg_out[i]; if (dov < 1) dov = 1;
        int div = deg_in[i];  if (div < 1) div = 1;
        out_norm[i] = rsqrtf((float)dov);
        in_norm[i]  = rsqrtf((float)div);
    }
}

// ---------------------------------------------------------------- 1-block scan
__global__ void scan_kernel(const int* __restrict__ deg, int* __restrict__ row_ptr) {
    __shared__ int sums[1024];
    const int T = 1024;
    int t = threadIdx.x;
    const int chunk = (N_NODES + T - 1) / T;   // 98
    int lo = t * chunk;
    int hi = lo + chunk; if (hi > N_NODES) hi = N_NODES;
    int s = 0;
    for (int i = lo; i < hi; i++) s += deg[i];
    sums[t] = s;
    __syncthreads();
    // Hillis-Steele inclusive scan
    for (int st = 1; st < T; st <<= 1) {
        int v = (t >= st) ? sums[t - st] : 0;
        __syncthreads();
        sums[t] += v;
        __syncthreads();
    }
    int base = (t == 0) ? 0 : sums[t - 1];
    for (int i = lo; i < hi; i++) { row_ptr[i] = base; base += deg[i]; }
    if (t == T - 1) row_ptr[N_NODES] = sums[T - 1];
}

// ---------------------------------------------------------------- CSR fill
__global__ void fill_kernel(const int* __restrict__ src, const int* __restrict__ dst,
                            const int* __restrict__ row_ptr, int* __restrict__ fill,
                            int* __restrict__ csr_src) {
    int e = blockIdx.x * blockDim.x + threadIdx.x;
    if (e < N_EDGES) {
        int d = dst[e];
        int pos = atomicAdd(&fill[d], 1);
        csr_src[row_ptr[d] + pos] = src[e];
    }
}

// ---------------------------------------------------------------- aggregation
// one wave per dst node; lane holds 2 of 128 feature columns
template<bool SRC_NORM>
__global__ __launch_bounds__(256) void aggregate_kernel(
    const float* __restrict__ x, const int* __restrict__ row_ptr,
    const int* __restrict__ csr_src, const float* __restrict__ out_norm,
    const float* __restrict__ in_norm, float* __restrict__ out) {
    int wave = threadIdx.x >> 6;
    int lane = threadIdx.x & 63;
    int n = blockIdx.x * 4 + wave;
    if (n >= N_NODES) return;
    int s0 = row_ptr[n], s1 = row_ptr[n + 1];
    const float2* xf = (const float2*)x;
    float2 acc = make_float2(0.f, 0.f);
    for (int i = s0; i < s1; i++) {
        int s = csr_src[i];
        float2 v = xf[(size_t)s * 64 + lane];
        if (SRC_NORM) {
            float sc = out_norm[s];
            acc.x = fmaf(v.x, sc, acc.x);
            acc.y = fmaf(v.y, sc, acc.y);
        } else {
            acc.x += v.x;
            acc.y += v.y;
        }
    }
    float inn = in_norm[n];
    ((float2*)out)[(size_t)n * 64 + lane] = make_float2(acc.x * inn, acc.y * inn);
}

// ---------------------------------------------------------------- f32 GEMM
// C[M,N] = A[M,K] @ B[K,N]  (B row-major K x N)
// EPI: 0 = none, 1 = +bias relu (aux = bias[N]), 2 = row-scale (aux = scale[M])
template<int EPI>
__global__ __launch_bounds__(256) void gemm64(
    const float* __restrict__ A, const float* __restrict__ B,
    const float* __restrict__ aux, float* __restrict__ C,
    int M, int K, int N) {
    __shared__ float As[64][65];   // [k][m], padded
    __shared__ float Bs[64][64];   // [k][n]
    int tid = threadIdx.x;
    int tx = tid & 15, ty = tid >> 4;
    int bm = blockIdx.y * 64, bn = blockIdx.x * 64;
    int lr = tid >> 4;   // load row group 0..15
    int lc = tid & 15;   // float4 col idx 0..15

    float acc[4][4];
    #pragma unroll
    for (int i = 0; i < 4; i++)
        #pragma unroll
        for (int j = 0; j < 4; j++) acc[i][j] = 0.f;

    for (int k0 = 0; k0 < K; k0 += 64) {
        #pragma unroll
        for (int r = 0; r < 4; r++) {
            int row = lr + r * 16;           // 0..63
            int grow = bm + row;
            float4 va;
            if (grow < M) va = *(const float4*)&A[(size_t)grow * K + k0 + lc * 4];
            else          va = make_float4(0.f, 0.f, 0.f, 0.f);
            As[lc * 4 + 0][row] = va.x;
            As[lc * 4 + 1][row] = va.y;
            As[lc * 4 + 2][row] = va.z;
            As[lc * 4 + 3][row] = va.w;
            float4 vb = *(const float4*)&B[(size_t)(k0 + row) * N + bn + lc * 4];
            *(float4*)&Bs[row][lc * 4] = vb;
        }
        __syncthreads();
        #pragma unroll
        for (int k = 0; k < 64; k++) {
            float4 a4 = *(const float4*)&As[k][ty * 4];
            float4 b4 = *(const float4*)&Bs[k][tx * 4];
            float a[4] = {a4.x, a4.y, a4.z, a4.w};
            float b[4] = {b4.x, b4.y, b4.z, b4.w};
            #pragma unroll
            for (int i = 0; i < 4; i++)
                #pragma unroll
                for (int j = 0; j < 4; j++)
                    acc[i][j] = fmaf(a[i], b[j], acc[i][j]);
        }
        __syncthreads();
    }

    #pragma unroll
    for (int i = 0; i < 4; i++) {
        int grow = bm + ty * 4 + i;
        if (grow >= M) continue;
        float4 v = make_float4(acc[i][0], acc[i][1], acc[i][2], acc[i][3]);
        if (EPI == 1) {
            int cb = bn + tx * 4;
            v.x = fmaxf(v.x + aux[cb + 0], 0.f);
            v.y = fmaxf(v.y + aux[cb + 1], 0.f);
            v.z = fmaxf(v.z + aux[cb + 2], 0.f);
            v.w = fmaxf(v.w + aux[cb + 3], 0.f);
        } else if (EPI == 2) {
            float sc = aux[grow];
            v.x *= sc; v.y *= sc; v.z *= sc; v.w *= sc;
        }
        *(float4*)&C[(size_t)grow * N + bn + tx * 4] = v;
    }
}

// ---------------------------------------------------------------- bias+relu
__global__ void bias_relu_kernel(const float* __restrict__ agg, const float* __restrict__ bias,
                                 float* __restrict__ out) {
    int idx = blockIdx.x * blockDim.x + threadIdx.x;   // over float4s
    if (idx >= N_NODES * 32) return;
    int c4 = idx & 31;
    float4 v = ((const float4*)agg)[idx];
    const float4 b = ((const float4*)bias)[c4];
    v.x = fmaxf(v.x + b.x, 0.f);
    v.y = fmaxf(v.y + b.y, 0.f);
    v.z = fmaxf(v.z + b.z, 0.f);
    v.w = fmaxf(v.w + b.w, 0.f);
    ((float4*)out)[idx] = v;
}

// ---------------------------------------------------------------- transpose 128x128
__global__ void transpose128(const float* __restrict__ in, float* __restrict__ out) {
    int t = blockIdx.x * blockDim.x + threadIdx.x;
    if (t >= 128 * 128) return;
    int j = t >> 7, k = t & 127;
    out[k * 128 + j] = in[t];
}

// ================================================================ launch
extern "C" void kernel_launch(void* const* d_in, const int* in_sizes, int n_in,
                              void* d_out, int out_size, void* d_ws, size_t ws_size,
                              hipStream_t stream) {
    const float* in_feat = (const float*)d_in[0];
    const int*   src     = (const int*)d_in[1];
    const int*   dst     = (const int*)d_in[2];
    const float* W1      = (const float*)d_in[3];
    const float* b1      = (const float*)d_in[4];
    const float* W2      = (const float*)d_in[5];
    const float* b2      = (const float*)d_in[6];
    const float* fc1_w   = (const float*)d_in[7];
    const float* fc2_w   = (const float*)d_in[8];

    float* out = (float*)d_out;
    float* h_out  = out;                                // [100000,128]
    float* feat1  = out + (size_t)N_NODES * 128;        // [100000,128]
    float* feat2  = out + (size_t)N_NODES * 256;        // [100000,128]
    // scratch aliases inside d_out (dead before final writes):
    float* h1 = out + (size_t)N_NODES * 128;            // [100000,256] = feat1+feat2 region
    float* x2 = out;                                    // [100000,128] = h region

    // workspace layout (all 16B-aligned chunks)
    int* deg_out = (int*)d_ws;                 // 100000
    int* deg_in  = deg_out + 100000;           // 100000
    int* fill    = deg_in + 100000;            // 100000
    int* row_ptr = fill + 100000;              // 100004 (padded)
    int* csr_src = row_ptr + 100004;           // 1600000
    float* out_norm = (float*)(csr_src + 1600000);  // 100000
    float* in_norm  = out_norm + 100000;            // 100000
    float* fcT1     = in_norm + 100000;             // 16384
    float* fcT2     = fcT1 + 16384;                 // 16384
    float* bufB     = fcT2 + 16384;                 // 12800000 (agg buffer)

    // 1. zero histograms + fill counters (3 x 100000 ints, contiguous)
    hipMemsetAsync(deg_out, 0, (size_t)300000 * sizeof(int), stream);

    // 2. degrees
    degree_kernel<<<(N_EDGES + 255) / 256, 256, 0, stream>>>(src, dst, deg_out, deg_in);

    // 3. norms
    norm_kernel<<<(N_NODES + 255) / 256, 256, 0, stream>>>(deg_out, deg_in, out_norm, in_norm);

    // 4. row_ptr = exclusive scan(deg_in)
    scan_kernel<<<1, 1024, 0, stream>>>(deg_in, row_ptr);

    // 5. CSR fill (by dst, stores src ids)
    fill_kernel<<<(N_EDGES + 255) / 256, 256, 0, stream>>>(src, dst, row_ptr, fill, csr_src);

    // 6. layer-1 aggregation: agg1 = in_norm * segsum(out_norm[s] * in_feat[s])
    aggregate_kernel<true><<<(N_NODES + 3) / 4, 256, 0, stream>>>(
        in_feat, row_ptr, csr_src, out_norm, in_norm, bufB);

    // 7. h1 = relu(agg1 @ W1 + b1)   [100000,256]
    {
        dim3 g(256 / 64, (N_NODES + 63) / 64);
        gemm64<1><<<g, 256, 0, stream>>>(bufB, W1, b1, h1, N_NODES, 128, 256);
    }

    // 8. x2 = (h1 @ W2) * out_norm   [100000,128]
    {
        dim3 g(128 / 64, (N_NODES + 63) / 64);
        gemm64<2><<<g, 256, 0, stream>>>(h1, W2, out_norm, x2, N_NODES, 256, 128);
    }

    // 9. layer-2 aggregation: agg2 = in_norm * segsum(x2[s])
    aggregate_kernel<false><<<(N_NODES + 3) / 4, 256, 0, stream>>>(
        x2, row_ptr, csr_src, out_norm, in_norm, bufB);

    // 10. h = relu(agg2 + b2) -> d_out[0:12.8M]  (overwrites x2, which is dead)
    bias_relu_kernel<<<(N_NODES * 32 + 255) / 256, 256, 0, stream>>>(bufB, b2, h_out);

    // 11. transpose fc weights (need B in [k][n] layout)
    transpose128<<<(128 * 128 + 255) / 256, 256, 0, stream>>>(fc1_w, fcT1);
    transpose128<<<(128 * 128 + 255) / 256, 256, 0, stream>>>(fc2_w, fcT2);

    // 12. feat1 = h @ fc1_w.T ; feat2 = h @ fc2_w.T  (overwrites h1 region, dead)
    {
        dim3 g(128 / 64, (N_NODES + 63) / 64);
        gemm64<0><<<g, 256, 0, stream>>>(h_out, fcT1, nullptr, feat1, N_NODES, 128, 128);
        gemm64<0><<<g, 256, 0, stream>>>(h_out, fcT2, nullptr, feat2, N_NODES, 128, 128);
    }
}

// Round 3
// 531.591 us; speedup vs baseline: 2.0477x; 2.0477x over previous
//
#include <hip/hip_runtime.h>

#define N_NODES 100000
#define N_EDGES 1600000

typedef __attribute__((ext_vector_type(8))) short short8;
typedef __attribute__((ext_vector_type(4))) float f32x4;

__device__ inline float bf2f(unsigned short h) {
    union { unsigned int u; float f; } v; v.u = ((unsigned int)h) << 16; return v.f;
}
__device__ inline unsigned short f2bf(float f) {
    union { unsigned int u; float f; } v; v.f = f;
    unsigned int u = v.u;
    return (unsigned short)((u + 0x7fffu + ((u >> 16) & 1u)) >> 16);
}

// ---------------------------------------------------------------- degree hist
__global__ void degree_kernel(const int* __restrict__ src, const int* __restrict__ dst,
                              int* __restrict__ deg_out, int* __restrict__ deg_in) {
    int e = blockIdx.x * blockDim.x + threadIdx.x;
    if (e < N_EDGES) {
        atomicAdd(&deg_out[src[e]], 1);
        atomicAdd(&deg_in[dst[e]], 1);
    }
}

// ---------------------------------------------------------------- norms
__global__ void norm_kernel(const int* __restrict__ deg_out, const int* __restrict__ deg_in,
                            float* __restrict__ out_norm, float* __restrict__ in_norm) {
    int i = blockIdx.x * blockDim.x + threadIdx.x;
    if (i < N_NODES) {
        int dov = deg_out[i]; if (dov < 1) dov = 1;
        int div = deg_in[i];  if (div < 1) div = 1;
        out_norm[i] = rsqrtf((float)dov);
        in_norm[i]  = rsqrtf((float)div);
    }
}

// ---------------------------------------------------------------- 1-block scan
__global__ void scan_kernel(const int* __restrict__ deg, int* __restrict__ row_ptr) {
    __shared__ int sums[1024];
    int t = threadIdx.x;
    int s = 0;
    if (t < 1000) {
        const int4* d4 = (const int4*)(deg + t * 100);   // 400B-aligned chunks
        #pragma unroll
        for (int i = 0; i < 25; i++) { int4 v = d4[i]; s += v.x + v.y + v.z + v.w; }
    }
    sums[t] = s;
    __syncthreads();
    for (int st = 1; st < 1024; st <<= 1) {
        int v = (t >= st) ? sums[t - st] : 0;
        __syncthreads();
        sums[t] += v;
        __syncthreads();
    }
    if (t < 1000) {
        int base = (t == 0) ? 0 : sums[t - 1];
        for (int i = 0; i < 100; i++) { row_ptr[t * 100 + i] = base; base += deg[t * 100 + i]; }
    }
    if (t == 1023) row_ptr[N_NODES] = sums[1023];
}

// ---------------------------------------------------------------- CSR fill
__global__ void fill_kernel(const int* __restrict__ src, const int* __restrict__ dst,
                            const int* __restrict__ row_ptr, int* __restrict__ fill,
                            int* __restrict__ csr_src) {
    int e = blockIdx.x * blockDim.x + threadIdx.x;
    if (e < N_EDGES) {
        int d = dst[e];
        int pos = atomicAdd(&fill[d], 1);
        csr_src[row_ptr[d] + pos] = src[e];
    }
}

// ---------------------------------------------------------------- weight prep
__global__ void tconv_kernel(const float* __restrict__ in, unsigned short* __restrict__ out,
                             int NN, int KK) {   // in [KK][NN] -> out [NN][KK] bf16
    int idx = blockIdx.x * blockDim.x + threadIdx.x;
    if (idx >= NN * KK) return;
    int n = idx / KK, k = idx % KK;
    out[idx] = f2bf(in[(size_t)k * NN + n]);
}
__global__ void conv_kernel(const float* __restrict__ in, unsigned short* __restrict__ out,
                            int total) {
    int idx = blockIdx.x * blockDim.x + threadIdx.x;
    if (idx < total) out[idx] = f2bf(in[idx]);
}

// ---------------------------------------------------------------- prescale x*out_norm -> bf16
__global__ void prescale_kernel(const float4* __restrict__ in, const float* __restrict__ out_norm,
                                ushort4* __restrict__ out) {
    int idx = blockIdx.x * blockDim.x + threadIdx.x;   // over 8B chunks (4 feats)
    if (idx >= N_NODES * 32) return;
    float sc = out_norm[idx >> 5];
    float4 v = in[idx];
    ushort4 o;
    o.x = f2bf(v.x * sc); o.y = f2bf(v.y * sc); o.z = f2bf(v.z * sc); o.w = f2bf(v.w * sc);
    out[idx] = o;
}

// ---------------------------------------------------------------- aggregation v2
// one wave per dst node; half-wave (32 lanes x ushort4 = 256B) covers one bf16 row;
// 2 halves x unroll 2 = 4 independent row gathers in flight.
// EPI 0: out_bf = bf16(sum * in_norm)          (agg1)
// EPI 1: v = relu(sum*in_norm + b2); half0 -> f32 out, half1 -> bf16 out   (agg2)
template<int EPI>
__global__ __launch_bounds__(256) void aggregate_bf(
    const ushort4* __restrict__ x, const int* __restrict__ row_ptr,
    const int* __restrict__ csr_src, const float* __restrict__ in_norm,
    const float* __restrict__ b2, float4* __restrict__ outF,
    ushort4* __restrict__ outB) {
    int wave = threadIdx.x >> 6, lane = threadIdx.x & 63;
    int n = blockIdx.x * 4 + wave;
    if (n >= N_NODES) return;
    int half = lane >> 5, cl = lane & 31;
    int s0 = row_ptr[n], s1 = row_ptr[n + 1];
    float ax = 0, ay = 0, az = 0, aw = 0;
    float bx = 0, by = 0, bz = 0, bw = 0;
    int i = s0 + half;
    for (; i + 2 < s1; i += 4) {
        int sA = csr_src[i], sB = csr_src[i + 2];
        ushort4 va = x[(size_t)sA * 32 + cl];
        ushort4 vb = x[(size_t)sB * 32 + cl];
        ax += bf2f(va.x); ay += bf2f(va.y); az += bf2f(va.z); aw += bf2f(va.w);
        bx += bf2f(vb.x); by += bf2f(vb.y); bz += bf2f(vb.z); bw += bf2f(vb.w);
    }
    if (i < s1) {
        ushort4 va = x[(size_t)csr_src[i] * 32 + cl];
        ax += bf2f(va.x); ay += bf2f(va.y); az += bf2f(va.z); aw += bf2f(va.w);
    }
    ax += bx; ay += by; az += bz; aw += bw;
    ax += __shfl_xor(ax, 32);
    ay += __shfl_xor(ay, 32);
    az += __shfl_xor(az, 32);
    aw += __shfl_xor(aw, 32);
    float inn = in_norm[n];
    if (EPI == 0) {
        if (half == 0) {
            ushort4 o;
            o.x = f2bf(ax * inn); o.y = f2bf(ay * inn);
            o.z = f2bf(az * inn); o.w = f2bf(aw * inn);
            outB[(size_t)n * 32 + cl] = o;
        }
    } else {
        float4 bv = ((const float4*)b2)[cl];
        float vx = fmaxf(fmaf(ax, inn, bv.x), 0.f);
        float vy = fmaxf(fmaf(ay, inn, bv.y), 0.f);
        float vz = fmaxf(fmaf(az, inn, bv.z), 0.f);
        float vw = fmaxf(fmaf(aw, inn, bv.w), 0.f);
        if (half == 0) {
            outF[(size_t)n * 32 + cl] = make_float4(vx, vy, vz, vw);
        } else {
            ushort4 o;
            o.x = f2bf(vx); o.y = f2bf(vy); o.z = f2bf(vz); o.w = f2bf(vw);
            outB[(size_t)n * 32 + cl] = o;
        }
    }
}

// ---------------------------------------------------------------- bf16 MFMA GEMM
// C[M x 128-tile] = A[M][K](bf16) @ Bt[N][K](bf16)^T; full-K in one block.
// Block: 256 thr = 4 waves, each wave 32 rows (2 x 16), 8 col-frags (128 cols).
// B^T staged in LDS, XOR-swizzled k-chunks -> conflict-free ds_read_b128.
// A frags loaded straight from global (no cross-wave A reuse), 1-deep prefetch.
// EPI: 0 = f32 store; 1 = bf16(relu(v+aux[col])); 2 = bf16(v*aux[row])
template<int K, int EPI>
__global__ __launch_bounds__(256) void gemm_mfma(
    const unsigned short* __restrict__ A, const unsigned short* __restrict__ Bt,
    const float* __restrict__ aux, void* __restrict__ Cv, int ldc, int M) {
    constexpr int CH = K / 8;                  // 16B chunks per row
    __shared__ short blds[128 * K];            // 32KB (K=128) / 64KB (K=256)
    int tid = threadIdx.x;
    int bn = blockIdx.x * 128;
    int bm = blockIdx.y * 128;
    {
        const short8* g = (const short8*)Bt;
        short8* l = (short8*)blds;
        for (int id = tid; id < 128 * CH; id += 256) {
            int col = id / CH, kc = id % CH;
            l[col * CH + (kc ^ (col & (CH - 1)))] = g[(size_t)(bn + col) * CH + kc];
        }
    }
    __syncthreads();
    int wm = tid >> 6, lane = tid & 63;
    int lr = lane & 15, kq = lane >> 4;        // A row / B col in frag; k-quarter
    int r0 = bm + wm * 32 + lr;
    int r1 = r0 + 16;
    const short8* A8 = (const short8*)A;
    size_t a0row = (size_t)(r0 < M ? r0 : 0) * CH;
    size_t a1row = (size_t)(r1 < M ? r1 : 0) * CH;
    const short8* l8 = (const short8*)blds;

    f32x4 acc[2][8];
    #pragma unroll
    for (int m = 0; m < 2; m++)
        #pragma unroll
        for (int j = 0; j < 8; j++) acc[m][j] = (f32x4)0.f;

    short8 a0 = A8[a0row + kq];
    short8 a1 = A8[a1row + kq];
    for (int kc2 = 0; kc2 < K / 32; kc2++) {
        int kc = kc2 * 4 + kq;
        short8 n0, n1;
        if (kc2 + 1 < K / 32) {                // prefetch next k-step
            n0 = A8[a0row + kc + 4];
            n1 = A8[a1row + kc + 4];
        }
        #pragma unroll
        for (int nj = 0; nj < 8; nj++) {
            int col = nj * 16 + lr;
            short8 b = l8[col * CH + (kc ^ (col & (CH - 1)))];
            acc[0][nj] = __builtin_amdgcn_mfma_f32_16x16x32_bf16(a0, b, acc[0][nj], 0, 0, 0);
            acc[1][nj] = __builtin_amdgcn_mfma_f32_16x16x32_bf16(a1, b, acc[1][nj], 0, 0, 0);
        }
        a0 = n0; a1 = n1;
    }

    #pragma unroll
    for (int mi = 0; mi < 2; mi++) {
        #pragma unroll
        for (int i = 0; i < 4; i++) {
            int gr = bm + wm * 32 + mi * 16 + kq * 4 + i;
            if (gr >= M) continue;
            float sc = (EPI == 2) ? aux[gr] : 0.f;
            #pragma unroll
            for (int nj = 0; nj < 8; nj++) {
                int col = bn + nj * 16 + lr;
                float v = acc[mi][nj][i];
                if (EPI == 0)
                    ((float*)Cv)[(size_t)gr * ldc + col] = v;
                else if (EPI == 1)
                    ((unsigned short*)Cv)[(size_t)gr * ldc + col] = f2bf(fmaxf(v + aux[col], 0.f));
                else
                    ((unsigned short*)Cv)[(size_t)gr * ldc + col] = f2bf(v * sc);
            }
        }
    }
}

// ================================================================ launch
extern "C" void kernel_launch(void* const* d_in, const int* in_sizes, int n_in,
                              void* d_out, int out_size, void* d_ws, size_t ws_size,
                              hipStream_t stream) {
    const float* in_feat = (const float*)d_in[0];
    const int*   src     = (const int*)d_in[1];
    const int*   dst     = (const int*)d_in[2];
    const float* W1      = (const float*)d_in[3];   // [128][256]
    const float* b1      = (const float*)d_in[4];
    const float* W2      = (const float*)d_in[5];   // [256][128]
    const float* b2      = (const float*)d_in[6];
    const float* fc1_w   = (const float*)d_in[7];   // [128][128], feat=h@fc^T -> Bt=fc directly
    const float* fc2_w   = (const float*)d_in[8];

    float* out = (float*)d_out;
    float* h_out = out;                              // [100000][128] f32 (final)
    float* feat1 = out + (size_t)12800000;           // final
    float* feat2 = out + (size_t)25600000;           // final
    // scratch aliases in d_out (lifetimes verified against writers):
    unsigned short* xs_bf   = (unsigned short*)out;                    // dies before agg2 writes h
    unsigned short* agg1_bf = (unsigned short*)(out + 6400000);        // dies before agg2 writes h
    unsigned short* h1_bf   = (unsigned short*)(out + 12800000);       // dies before feat1 written
    unsigned short* x2_bf   = (unsigned short*)(out + 25600000);       // dies before feat2 written

    int* deg_out = (int*)d_ws;
    int* deg_in  = deg_out + 100000;
    int* fill    = deg_in + 100000;
    int* row_ptr = fill + 100000;                    // 100004
    int* csr_src = row_ptr + 100004;                 // 1600000
    float* out_norm = (float*)(csr_src + 1600000);
    float* in_norm  = out_norm + 100000;
    unsigned short* Wt1  = (unsigned short*)(in_norm + 100000);  // [256][128]
    unsigned short* Wt2  = Wt1 + 32768;                          // [128][256]
    unsigned short* fc1b = Wt2 + 32768;                          // [128][128]
    unsigned short* fc2b = fc1b + 16384;
    unsigned short* h_bf = fc2b + 16384;                         // [100000][128]

    hipMemsetAsync(deg_out, 0, (size_t)300000 * sizeof(int), stream);
    degree_kernel<<<(N_EDGES + 255) / 256, 256, 0, stream>>>(src, dst, deg_out, deg_in);
    norm_kernel<<<(N_NODES + 255) / 256, 256, 0, stream>>>(deg_out, deg_in, out_norm, in_norm);
    scan_kernel<<<1, 1024, 0, stream>>>(deg_in, row_ptr);
    fill_kernel<<<(N_EDGES + 255) / 256, 256, 0, stream>>>(src, dst, row_ptr, fill, csr_src);

    tconv_kernel<<<128, 256, 0, stream>>>(W1, Wt1, 256, 128);
    tconv_kernel<<<128, 256, 0, stream>>>(W2, Wt2, 128, 256);
    conv_kernel<<<64, 256, 0, stream>>>(fc1_w, fc1b, 16384);
    conv_kernel<<<64, 256, 0, stream>>>(fc2_w, fc2b, 16384);

    prescale_kernel<<<12500, 256, 0, stream>>>((const float4*)in_feat, out_norm, (ushort4*)xs_bf);

    aggregate_bf<0><<<25000, 256, 0, stream>>>((const ushort4*)xs_bf, row_ptr, csr_src,
                                               in_norm, nullptr, nullptr, (ushort4*)agg1_bf);

    gemm_mfma<128, 1><<<dim3(2, 782), 256, 0, stream>>>(agg1_bf, Wt1, b1, h1_bf, 256, N_NODES);
    gemm_mfma<256, 2><<<dim3(1, 782), 256, 0, stream>>>(h1_bf, Wt2, out_norm, x2_bf, 128, N_NODES);

    aggregate_bf<1><<<25000, 256, 0, stream>>>((const ushort4*)x2_bf, row_ptr, csr_src,
                                               in_norm, b2, (float4*)h_out, (ushort4*)h_bf);

    gemm_mfma<128, 0><<<dim3(1, 782), 256, 0, stream>>>(h_bf, fc1b, nullptr, feat1, 128, N_NODES);
    gemm_mfma<128, 0><<<dim3(1, 782), 256, 0, stream>>>(h_bf, fc2b, nullptr, feat2, 128, N_NODES);
}